// Round 2
// baseline (571.479 us; speedup 1.0000x reference)
//
#include <hip/hip_runtime.h>

typedef __bf16 bf16;
typedef float f32x4 __attribute__((ext_vector_type(4)));
typedef bf16 bf16x8 __attribute__((ext_vector_type(8)));

#define BB 512
#define LL 50
#define NN 64
#define EE 16
#define HH 128
#define DD 256
#define ITEMS 100000
#define EPSV 1e-12f

// ---------------- K0: detect float dtype. hn_adj is exactly {0,1}.
// fp32 words are all 0x00000000 / 0x3F800000; bf16-pair words hit other patterns ~25%/word.
__global__ void k_detect(const unsigned int* __restrict__ adj_words, int* __restrict__ flag) {
    __shared__ int s;
    if (threadIdx.x == 0) s = 0;
    __syncthreads();
    int local = 0;
    for (int i = 0; i < 16; i++) {
        unsigned int w = adj_words[threadIdx.x * 16 + i];
        if (w != 0u && w != 0x3F800000u) local = 1;
    }
    if (local) s = 1;  // benign race
    __syncthreads();
    if (threadIdx.x == 0) flag[0] = s;  // 1 = bf16, 0 = fp32
}

// ---------------- K1: nodes_hidden_in = l2norm(embedding[nodes]) -> fp32 [B*N,128]
template <typename T>
__device__ __forceinline__ void nodes_norm_body(const int* nodes, const T* emb, float* nodes_h) {
    int row  = blockIdx.x * 4 + (threadIdx.x >> 6);  // 0..32767
    int lane = threadIdx.x & 63;
    int node = nodes[row];
    const T* src = emb + (long)node * HH;
    float x0 = (float)src[lane * 2], x1 = (float)src[lane * 2 + 1];
    float s = x0 * x0 + x1 * x1;
    for (int o = 32; o; o >>= 1) s += __shfl_xor(s, o);
    float inv = 1.0f / fmaxf(sqrtf(s), EPSV);
    float* dst = nodes_h + (long)row * HH;
    dst[lane * 2] = x0 * inv;
    dst[lane * 2 + 1] = x1 * inv;
}
__global__ void k_nodes_norm(const int* __restrict__ nodes, const void* __restrict__ emb,
                             const int* __restrict__ flag, float* __restrict__ nodes_h) {
    if (*flag) nodes_norm_body<bf16>(nodes, (const bf16*)emb, nodes_h);
    else       nodes_norm_body<float>(nodes, (const float*)emb, nodes_h);
}

// ---------------- K2: hgnn, one block per batch, 2 steps, in-place on nodes_h
template <typename T>
__device__ __forceinline__ void hgnn_body(const T* hn_adj, const T* w_edge, const T* w_node,
                                          float* nodes_h, float (*s_nh)[HH], float (*s_ea)[HH],
                                          float (*s_eh)[HH], float (*s_adj)[EE],
                                          float* s_rde, float* s_rdn) {
    int b = blockIdx.x, t = threadIdx.x;
    float* nh_g = nodes_h + (long)b * NN * HH;
    for (int i = t; i < NN * HH / 4; i += 256)
        ((f32x4*)s_nh)[i] = ((const f32x4*)nh_g)[i];
    const T* adj_g = hn_adj + (long)b * NN * EE;
    for (int i = t; i < NN * EE; i += 256)
        ((float*)s_adj)[i] = (float)adj_g[i];
    __syncthreads();
    if (t < EE) {
        float s = 0;
        for (int n = 0; n < NN; n++) s += s_adj[n][t];
        s_rde[t] = 1.0f / fmaxf(s, 1.0f);
    } else if (t >= 64 && t < 64 + NN) {
        int n = t - 64;
        float s = 0;
        for (int e = 0; e < EE; e++) s += s_adj[n][e];
        s_rdn[n] = 1.0f / fmaxf(s, 1.0f);
    }
    __syncthreads();
    int d = t & 127, half = t >> 7;
    for (int step = 0; step < 2; step++) {
        for (int i = 0; i < 8; i++) {  // e_agg = (adj^T @ n_h)/deg_e
            int e = half * 8 + i;
            float acc = 0;
            for (int n = 0; n < NN; n++) acc += s_adj[n][e] * s_nh[n][d];
            s_ea[e][d] = acc * s_rde[e];
        }
        __syncthreads();
        {   // e_h = s_ea @ w_edge
            float acc[8] = {0, 0, 0, 0, 0, 0, 0, 0};
            for (int k = 0; k < HH; k++) {
                float wv = (float)w_edge[k * HH + d];
                for (int i = 0; i < 8; i++) acc[i] += s_ea[half * 8 + i][k] * wv;
            }
            for (int i = 0; i < 8; i++) s_eh[half * 8 + i][d] = acc[i];
        }
        __syncthreads();
        {   // ew = e_h @ w_node
            float acc[8] = {0, 0, 0, 0, 0, 0, 0, 0};
            for (int k = 0; k < HH; k++) {
                float wv = (float)w_node[k * HH + d];
                for (int i = 0; i < 8; i++) acc[i] += s_eh[half * 8 + i][k] * wv;
            }
            for (int i = 0; i < 8; i++) s_ea[half * 8 + i][d] = acc[i];
        }
        __syncthreads();
        for (int i = 0; i < 32; i++) {  // n_h = (adj @ ew)/deg_n
            int n = half * 32 + i;
            float acc = 0;
            for (int e = 0; e < EE; e++) acc += s_adj[n][e] * s_ea[e][d];
            s_nh[n][d] = acc * s_rdn[n];
        }
        __syncthreads();
    }
    for (int i = t; i < NN * HH / 4; i += 256)
        ((f32x4*)nh_g)[i] = ((f32x4*)s_nh)[i];
}
__global__ __launch_bounds__(256) void k_hgnn(const void* __restrict__ hn_adj,
                                              const void* __restrict__ w_edge,
                                              const void* __restrict__ w_node,
                                              const int* __restrict__ flag,
                                              float* __restrict__ nodes_h) {
    __shared__ float s_nh[NN][HH];
    __shared__ float s_ea[EE][HH];
    __shared__ float s_eh[EE][HH];
    __shared__ float s_adj[NN][EE];
    __shared__ float s_rde[EE], s_rdn[NN];
    if (*flag) hgnn_body<bf16>((const bf16*)hn_adj, (const bf16*)w_edge, (const bf16*)w_node,
                               nodes_h, s_nh, s_ea, s_eh, s_adj, s_rde, s_rdn);
    else       hgnn_body<float>((const float*)hn_adj, (const float*)w_edge, (const float*)w_node,
                                nodes_h, s_nh, s_ea, s_eh, s_adj, s_rde, s_rdn);
}

// ---------------- K3: seq_hidden = l2norm(concat(gathers)) -> fp32 [B*L,256]
__global__ void k_seq_hidden(const int* __restrict__ alias_item, const int* __restrict__ alias_cate,
                             const float* __restrict__ nodes_h, float* __restrict__ seq_h) {
    int row  = blockIdx.x * 4 + (threadIdx.x >> 6);  // 0..25599
    int lane = threadIdx.x & 63;
    int b = row / LL;
    int ai = alias_item[row], ac = alias_cate[row];
    const float* iv = nodes_h + ((long)b * NN + ai) * HH;
    const float* cv = nodes_h + ((long)b * NN + ac) * HH;
    float x0 = iv[lane * 2], x1 = iv[lane * 2 + 1];
    float y0 = cv[lane * 2], y1 = cv[lane * 2 + 1];
    float s = x0 * x0 + x1 * x1 + y0 * y0 + y1 * y1;
    for (int o = 32; o; o >>= 1) s += __shfl_xor(s, o);
    float inv = 1.0f / fmaxf(sqrtf(s), EPSV);
    float* dst = seq_h + (long)row * DD;
    dst[lane * 2] = x0 * inv;
    dst[lane * 2 + 1] = x1 * inv;
    dst[128 + lane * 2] = y0 * inv;
    dst[128 + lane * 2 + 1] = y1 * inv;
}

// ---------------- K4: attention readout -> so_n bf16 [B,256] (l2-normalized)
template <typename T>
__device__ __forceinline__ void attn_body(const int* item_seq, const float* seq_h,
                                          const T* q1_w, const T* q1_b, const T* q2_w, const T* v_w,
                                          bf16* so_n, float (*s_sh)[DD], float* s_alpha,
                                          float* s_flag, float (*s_red)[32], int* s_li) {
    int b = blockIdx.x, t = threadIdx.x;
    const float* sh_g = seq_h + (long)b * LL * DD;
    for (int i = t; i < LL * DD / 4; i += 256)
        ((f32x4*)s_sh)[i] = ((const f32x4*)sh_g)[i];
    if (t < LL) s_flag[t] = (item_seq[b * LL + t] > 0) ? 1.0f : 0.0f;
    __syncthreads();
    if (t == 0) {
        int c = 0;
        for (int l = 0; l < LL; l++) c += (s_flag[l] > 0.5f);
        *s_li = max(c - 1, 0);
    }
    __syncthreads();
    int li = *s_li;
    int d = t;
    float q1d = (float)q1_b[d];
    for (int k = 0; k < DD; k++) q1d += s_sh[li][k] * (float)q1_w[k * DD + d];
    float vwd = (float)v_w[d];
    int wv = t >> 6, lane = t & 63;
    for (int p = 0; p < 2; p++) {
        float acc[25];
        for (int i = 0; i < 25; i++) acc[i] = 0;
        int l0 = p * 25;
        for (int k = 0; k < DD; k++) {
            float wkd = (float)q2_w[k * DD + d];
            for (int i = 0; i < 25; i++) acc[i] += s_sh[l0 + i][k] * wkd;
        }
        for (int i = 0; i < 25; i++) {
            float val = 1.0f / (1.0f + __expf(-(q1d + acc[i])));
            float contrib = val * vwd;
            for (int o = 32; o; o >>= 1) contrib += __shfl_xor(contrib, o);
            if (lane == 0) s_red[wv][i] = contrib;
        }
        __syncthreads();
        if (t < 25) s_alpha[l0 + t] = s_red[0][t] + s_red[1][t] + s_red[2][t] + s_red[3][t];
        __syncthreads();
    }
    float so = 0;
    for (int l = 0; l < LL; l++) so += s_alpha[l] * s_flag[l] * s_sh[l][d];
    float ss = so * so;
    for (int o = 32; o; o >>= 1) ss += __shfl_xor(ss, o);
    if (lane == 0) s_red[0][wv] = ss;
    __syncthreads();
    float tot = s_red[0][0] + s_red[0][1] + s_red[0][2] + s_red[0][3];
    float inv = 1.0f / fmaxf(sqrtf(tot), EPSV);
    so_n[b * DD + d] = (bf16)(so * inv);
}
__global__ __launch_bounds__(256) void k_attn(const int* __restrict__ item_seq,
                                              const float* __restrict__ seq_h,
                                              const void* __restrict__ q1_w, const void* __restrict__ q1_b,
                                              const void* __restrict__ q2_w, const void* __restrict__ v_w,
                                              const int* __restrict__ flag, bf16* __restrict__ so_n) {
    __shared__ float s_sh[LL][DD];
    __shared__ float s_alpha[LL];
    __shared__ float s_flag[LL];
    __shared__ float s_red[4][32];
    __shared__ int s_li;
    if (*flag) attn_body<bf16>(item_seq, seq_h, (const bf16*)q1_w, (const bf16*)q1_b,
                               (const bf16*)q2_w, (const bf16*)v_w, so_n,
                               s_sh, s_alpha, s_flag, s_red, &s_li);
    else       attn_body<float>(item_seq, seq_h, (const float*)q1_w, (const float*)q1_b,
                                (const float*)q2_w, (const float*)v_w, so_n,
                                s_sh, s_alpha, s_flag, s_red, &s_li);
}

// ---------------- K6: scores = 16 * so_n @ l2norm(item_emb)^T  (item_emb normalized inline)
#define NT 32
#define PAD 8
template <typename T, typename TO>
__device__ __forceinline__ void scores_body(const bf16* so_n, const T* emb, const int* item_cates,
                                            TO* out, bf16 (*sB)[DD + PAD], bf16 (*sA)[DD + PAD]) {
    int t = threadIdx.x;
    long n0 = (long)blockIdx.x * NT;
    {   // stage + normalize B tile: 32 item rows, 8 threads per row
        int r = t >> 3, j = t & 7;
        long item = n0 + r;
        int cate = item_cates[item];
        const T* ip = emb + item * HH;
        const T* cp = emb + (long)cate * HH;
        float v[32];
        for (int k = 0; k < 16; k++) v[k]      = (float)ip[j * 16 + k];
        for (int k = 0; k < 16; k++) v[16 + k] = (float)cp[j * 16 + k];
        float s = 0;
        for (int k = 0; k < 32; k++) s += v[k] * v[k];
        s += __shfl_xor(s, 1); s += __shfl_xor(s, 2); s += __shfl_xor(s, 4);
        float inv = 1.0f / fmaxf(sqrtf(s), EPSV);
        for (int k = 0; k < 16; k++) sB[r][j * 16 + k]       = (bf16)(v[k] * inv);
        for (int k = 0; k < 16; k++) sB[r][128 + j * 16 + k] = (bf16)(v[16 + k] * inv);
    }
    int w = t >> 6, lane = t & 63, quad = lane >> 4, r16 = lane & 15;
    for (int m0 = 0; m0 < 8; m0++) {
        int mbase = m0 * 64;
        __syncthreads();  // first iter: also covers sB staging
        {
            int c = t & 31, r = t >> 5;
            for (int rr = r; rr < 64; rr += 8)
                *(f32x4*)&sA[rr][c * 8] = *(const f32x4*)&so_n[(long)(mbase + rr) * DD + c * 8];
        }
        __syncthreads();
        f32x4 acc0 = {0, 0, 0, 0}, acc1 = {0, 0, 0, 0};
        for (int kc = 0; kc < 8; kc++) {
            bf16x8 a  = *(bf16x8*)&sA[w * 16 + r16][kc * 32 + quad * 8];
            bf16x8 b0 = *(bf16x8*)&sB[r16][kc * 32 + quad * 8];
            bf16x8 b1 = *(bf16x8*)&sB[16 + r16][kc * 32 + quad * 8];
            acc0 = __builtin_amdgcn_mfma_f32_16x16x32_bf16(a, b0, acc0, 0, 0, 0);
            acc1 = __builtin_amdgcn_mfma_f32_16x16x32_bf16(a, b1, acc1, 0, 0, 0);
        }
        int row_base = mbase + w * 16 + quad * 4;
        for (int r = 0; r < 4; r++) {
            out[(long)(row_base + r) * ITEMS + n0 + r16]      = (TO)(acc0[r] * 16.0f);
            out[(long)(row_base + r) * ITEMS + n0 + r16 + 16] = (TO)(acc1[r] * 16.0f);
        }
    }
}
__global__ __launch_bounds__(256) void k_scores(const bf16* __restrict__ so_n,
                                                const void* __restrict__ emb,
                                                const int* __restrict__ item_cates,
                                                const int* __restrict__ flag,
                                                void* __restrict__ out) {
    __shared__ bf16 sB[NT][DD + PAD];
    __shared__ bf16 sA[64][DD + PAD];
    if (*flag) scores_body<bf16, bf16>(so_n, (const bf16*)emb, item_cates, (bf16*)out, sB, sA);
    else       scores_body<float, float>(so_n, (const float*)emb, item_cates, (float*)out, sB, sA);
}

extern "C" void kernel_launch(void* const* d_in, const int* in_sizes, int n_in,
                              void* d_out, int out_size, void* d_ws, size_t ws_size,
                              hipStream_t stream) {
    const int* item_seq   = (const int*)d_in[0];
    const int* nodes      = (const int*)d_in[2];
    const void* hn_adj    = d_in[3];
    const int* alias_item = (const int*)d_in[4];
    const int* alias_cate = (const int*)d_in[5];
    const void* emb       = d_in[6];
    const int* item_cates = (const int*)d_in[7];
    const void* w_edge    = d_in[8];
    const void* w_node    = d_in[9];
    const void* q1_w      = d_in[10];
    const void* q1_b      = d_in[11];
    const void* q2_w      = d_in[12];
    const void* v_w       = d_in[13];

    char* ws = (char*)d_ws;
    int*   flag    = (int*)ws;                          // 256 B slot
    float* nodes_h = (float*)(ws + 256);                // 16,777,216 B
    float* seq_h   = (float*)(ws + 256 + 16777216);     // 26,214,400 B
    bf16*  so_n    = (bf16*)(ws + 256 + 16777216 + 26214400);  // 262,144 B  (total ~43.3 MB)

    k_detect<<<1, 256, 0, stream>>>((const unsigned int*)hn_adj, flag);
    k_nodes_norm<<<8192, 256, 0, stream>>>(nodes, emb, flag, nodes_h);
    k_hgnn<<<512, 256, 0, stream>>>(hn_adj, w_edge, w_node, flag, nodes_h);
    k_seq_hidden<<<6400, 256, 0, stream>>>(alias_item, alias_cate, nodes_h, seq_h);
    k_attn<<<512, 256, 0, stream>>>(item_seq, seq_h, q1_w, q1_b, q2_w, v_w, flag, so_n);
    k_scores<<<3125, 256, 0, stream>>>(so_n, emb, item_cates, flag, d_out);
}

// Round 4
// 483.731 us; speedup vs baseline: 1.1814x; 1.1814x over previous
//
#include <hip/hip_runtime.h>

typedef __bf16 bf16;
typedef float f32x4 __attribute__((ext_vector_type(4)));
typedef bf16 bf16x8 __attribute__((ext_vector_type(8)));
typedef bf16 bf16x4 __attribute__((ext_vector_type(4)));

#define BB 512
#define LL 50
#define NN 64
#define EE 16
#define HH 128
#define DD 256
#define ITEMS 100000
#define EPSV 1e-12f

// ---------------- K0: detect float dtype (race-free). hn_adj is exactly {0,1}.
__global__ void k_detect(const unsigned int* __restrict__ adj_words, int* __restrict__ flag) {
    __shared__ int s_w[4];
    int t = threadIdx.x;
    int local = 0;
    for (int i = 0; i < 16; i++) {
        unsigned int w = adj_words[t * 16 + i];
        if (w != 0u && w != 0x3F800000u) local = 1;
    }
    unsigned long long m = __ballot(local);
    if ((t & 63) == 0) s_w[t >> 6] = (m != 0ull) ? 1 : 0;
    __syncthreads();
    if (t == 0) flag[0] = (s_w[0] | s_w[1] | s_w[2] | s_w[3]);  // 1 = bf16, 0 = fp32
}

// ---------------- K1: nodes_hidden_in = l2norm(embedding[nodes]) -> fp32 [B*N,128]
template <typename T>
__device__ __forceinline__ void nodes_norm_body(const int* nodes, const T* emb, float* nodes_h) {
    int row  = blockIdx.x * 4 + (threadIdx.x >> 6);
    int lane = threadIdx.x & 63;
    int node = nodes[row];
    const T* src = emb + (long)node * HH;
    float x0 = (float)src[lane * 2], x1 = (float)src[lane * 2 + 1];
    float s = x0 * x0 + x1 * x1;
    for (int o = 32; o; o >>= 1) s += __shfl_xor(s, o);
    float inv = 1.0f / fmaxf(sqrtf(s), EPSV);
    float* dst = nodes_h + (long)row * HH;
    dst[lane * 2] = x0 * inv;
    dst[lane * 2 + 1] = x1 * inv;
}
__global__ void k_nodes_norm(const int* __restrict__ nodes, const void* __restrict__ emb,
                             const int* __restrict__ flag, float* __restrict__ nodes_h) {
    if (*flag) nodes_norm_body<bf16>(nodes, (const bf16*)emb, nodes_h);
    else       nodes_norm_body<float>(nodes, (const float*)emb, nodes_h);
}

// ---------------- K2: hgnn, one block per batch, 2 steps, in-place on nodes_h
template <typename T>
__device__ __forceinline__ void hgnn_body(const T* hn_adj, const T* w_edge, const T* w_node,
                                          float* nodes_h, float (*s_nh)[HH], float (*s_ea)[HH],
                                          float (*s_eh)[HH], float (*s_adj)[EE],
                                          float* s_rde, float* s_rdn) {
    int b = blockIdx.x, t = threadIdx.x;
    float* nh_g = nodes_h + (long)b * NN * HH;
    for (int i = t; i < NN * HH / 4; i += 256)
        ((f32x4*)s_nh)[i] = ((const f32x4*)nh_g)[i];
    const T* adj_g = hn_adj + (long)b * NN * EE;
    for (int i = t; i < NN * EE; i += 256)
        ((float*)s_adj)[i] = (float)adj_g[i];
    __syncthreads();
    if (t < EE) {
        float s = 0;
        for (int n = 0; n < NN; n++) s += s_adj[n][t];
        s_rde[t] = 1.0f / fmaxf(s, 1.0f);
    } else if (t >= 64 && t < 64 + NN) {
        int n = t - 64;
        float s = 0;
        for (int e = 0; e < EE; e++) s += s_adj[n][e];
        s_rdn[n] = 1.0f / fmaxf(s, 1.0f);
    }
    __syncthreads();
    int d = t & 127, half = t >> 7;
    for (int step = 0; step < 2; step++) {
        for (int i = 0; i < 8; i++) {
            int e = half * 8 + i;
            float acc = 0;
            for (int n = 0; n < NN; n++) acc += s_adj[n][e] * s_nh[n][d];
            s_ea[e][d] = acc * s_rde[e];
        }
        __syncthreads();
        {
            float acc[8] = {0, 0, 0, 0, 0, 0, 0, 0};
            for (int k = 0; k < HH; k++) {
                float wv = (float)w_edge[k * HH + d];
                for (int i = 0; i < 8; i++) acc[i] += s_ea[half * 8 + i][k] * wv;
            }
            for (int i = 0; i < 8; i++) s_eh[half * 8 + i][d] = acc[i];
        }
        __syncthreads();
        {
            float acc[8] = {0, 0, 0, 0, 0, 0, 0, 0};
            for (int k = 0; k < HH; k++) {
                float wv = (float)w_node[k * HH + d];
                for (int i = 0; i < 8; i++) acc[i] += s_eh[half * 8 + i][k] * wv;
            }
            for (int i = 0; i < 8; i++) s_ea[half * 8 + i][d] = acc[i];
        }
        __syncthreads();
        for (int i = 0; i < 32; i++) {
            int n = half * 32 + i;
            float acc = 0;
            for (int e = 0; e < EE; e++) acc += s_adj[n][e] * s_ea[e][d];
            s_nh[n][d] = acc * s_rdn[n];
        }
        __syncthreads();
    }
    for (int i = t; i < NN * HH / 4; i += 256)
        ((f32x4*)nh_g)[i] = ((f32x4*)s_nh)[i];
}
__global__ __launch_bounds__(256) void k_hgnn(const void* __restrict__ hn_adj,
                                              const void* __restrict__ w_edge,
                                              const void* __restrict__ w_node,
                                              const int* __restrict__ flag,
                                              float* __restrict__ nodes_h) {
    __shared__ float s_nh[NN][HH];
    __shared__ float s_ea[EE][HH];
    __shared__ float s_eh[EE][HH];
    __shared__ float s_adj[NN][EE];
    __shared__ float s_rde[EE], s_rdn[NN];
    if (*flag) hgnn_body<bf16>((const bf16*)hn_adj, (const bf16*)w_edge, (const bf16*)w_node,
                               nodes_h, s_nh, s_ea, s_eh, s_adj, s_rde, s_rdn);
    else       hgnn_body<float>((const float*)hn_adj, (const float*)w_edge, (const float*)w_node,
                                nodes_h, s_nh, s_ea, s_eh, s_adj, s_rde, s_rdn);
}

// ---------------- K_prep: q2wT[n][k] = (bf16) q2_w[k][n]
template <typename T>
__device__ __forceinline__ void prep_body(const T* q2w, bf16* q2wT) {
    int n = blockIdx.x, k = threadIdx.x;
    q2wT[n * DD + k] = (bf16)(float)q2w[k * DD + n];
}
__global__ void k_prep(const void* __restrict__ q2w, const int* __restrict__ flag,
                       bf16* __restrict__ q2wT) {
    if (*flag) prep_body<bf16>((const bf16*)q2w, q2wT);
    else       prep_body<float>((const float*)q2w, q2wT);
}

// ---------------- K4 v3: fused seq_hidden gather+norm + MFMA attention -> so_n bf16 [B,256]
#define APAD 8
template <typename T>
__device__ __forceinline__ void attn_body(const int* item_seq, const int* alias_item,
                                          const int* alias_cate, const float* nodes_h,
                                          const T* q1_w, const T* q1_b, const T* v_w,
                                          const bf16* q2wT, bf16* so_n,
                                          bf16 (*sA)[DD + APAD], float* s_q1, float* s_vw,
                                          float* s_ht, float (*s_alpha_w)[64], float* s_alpha,
                                          float* s_flag, float* s_red, int* s_ai, int* s_ac,
                                          int* s_li) {
    int b = blockIdx.x, t = threadIdx.x;
    int w = t >> 6, lane = t & 63, quad = lane >> 4, r16 = lane & 15;

    if (t < LL) {
        s_ai[t] = alias_item[b * LL + t];
        s_ac[t] = alias_cate[b * LL + t];
        s_flag[t] = (item_seq[b * LL + t] > 0) ? 1.0f : 0.0f;
    }
    s_vw[t] = (float)v_w[t];
    __syncthreads();

    // gather + l2norm rows -> sA bf16 (one wave per row; rows >= 50 zeroed)
    for (int l = w; l < 64; l += 4) {
        if (l < LL) {
            const float* iv = nodes_h + ((long)b * NN + s_ai[l]) * HH;
            const float* cv = nodes_h + ((long)b * NN + s_ac[l]) * HH;
            float x0 = iv[lane * 2], x1 = iv[lane * 2 + 1];
            float y0 = cv[lane * 2], y1 = cv[lane * 2 + 1];
            float s = x0 * x0 + x1 * x1 + y0 * y0 + y1 * y1;
            for (int o = 32; o; o >>= 1) s += __shfl_xor(s, o);
            float inv = 1.0f / fmaxf(sqrtf(s), EPSV);
            sA[l][lane * 2]       = (bf16)(x0 * inv);
            sA[l][lane * 2 + 1]   = (bf16)(x1 * inv);
            sA[l][128 + lane * 2]     = (bf16)(y0 * inv);
            sA[l][128 + lane * 2 + 1] = (bf16)(y1 * inv);
        } else {
            sA[l][lane * 2]       = (bf16)0.f;
            sA[l][lane * 2 + 1]   = (bf16)0.f;
            sA[l][128 + lane * 2]     = (bf16)0.f;
            sA[l][128 + lane * 2 + 1] = (bf16)0.f;
        }
    }
    if (t == 0) {
        int c = 0;
        for (int l = 0; l < LL; l++) c += (s_flag[l] > 0.5f);
        *s_li = max(c - 1, 0);
    }
    __syncthreads();
    int li = *s_li;

    // ht (fp32, exact): gather row li, l2norm via block reduction
    float htv;
    {
        int ai = s_ai[li], ac = s_ac[li];
        htv = (t < 128) ? nodes_h[((long)b * NN + ai) * HH + t]
                        : nodes_h[((long)b * NN + ac) * HH + (t - 128)];
        float ss = htv * htv;
        for (int o = 32; o; o >>= 1) ss += __shfl_xor(ss, o);
        if (lane == 0) s_red[w] = ss;
    }
    __syncthreads();
    {
        float tot = s_red[0] + s_red[1] + s_red[2] + s_red[3];
        s_ht[t] = htv / fmaxf(sqrtf(tot), EPSV);
    }
    __syncthreads();
    // q1[d] = bias[d] + ht @ q1_w[:,d]
    {
        float q1d = (float)q1_b[t];
        for (int k = 0; k < DD; k++) q1d += s_ht[k] * (float)q1_w[k * DD + t];
        s_q1[t] = q1d;
    }
    __syncthreads();

    // MFMA: q2-tile [64 rows l][64 cols d] per wave (wave w covers d in [w*64, w*64+64))
    f32x4 acc[4][4];
#pragma unroll
    for (int mt = 0; mt < 4; mt++)
#pragma unroll
        for (int nt = 0; nt < 4; nt++) acc[mt][nt] = (f32x4){0, 0, 0, 0};
#pragma unroll
    for (int kc = 0; kc < 8; kc++) {
        bf16x8 bfr[4], afr[4];
#pragma unroll
        for (int nt = 0; nt < 4; nt++)
            bfr[nt] = *(const bf16x8*)&q2wT[(long)(w * 64 + nt * 16 + r16) * DD + kc * 32 + quad * 8];
#pragma unroll
        for (int mt = 0; mt < 4; mt++)
            afr[mt] = *(const bf16x8*)&sA[mt * 16 + r16][kc * 32 + quad * 8];
#pragma unroll
        for (int mt = 0; mt < 4; mt++)
#pragma unroll
            for (int nt = 0; nt < 4; nt++)
                acc[mt][nt] = __builtin_amdgcn_mfma_f32_16x16x32_bf16(afr[mt], bfr[nt], acc[mt][nt], 0, 0, 0);
    }
    // epilogue: alpha_l = sum_d sigmoid(q1[d] + q2[l,d]) * v_w[d]
    float part[4][4];
#pragma unroll
    for (int mt = 0; mt < 4; mt++)
#pragma unroll
        for (int r = 0; r < 4; r++) part[mt][r] = 0.f;
#pragma unroll
    for (int nt = 0; nt < 4; nt++) {
        int d = w * 64 + nt * 16 + r16;
        float q1v = s_q1[d], vw = s_vw[d];
#pragma unroll
        for (int mt = 0; mt < 4; mt++)
#pragma unroll
            for (int r = 0; r < 4; r++) {
                float sig = 1.0f / (1.0f + __expf(-(q1v + acc[mt][nt][r])));
                part[mt][r] += sig * vw;
            }
    }
#pragma unroll
    for (int mt = 0; mt < 4; mt++)
#pragma unroll
        for (int r = 0; r < 4; r++) {
            float v = part[mt][r];
            v += __shfl_xor(v, 1); v += __shfl_xor(v, 2);
            v += __shfl_xor(v, 4); v += __shfl_xor(v, 8);
            part[mt][r] = v;
        }
    if (r16 == 0) {
#pragma unroll
        for (int mt = 0; mt < 4; mt++)
#pragma unroll
            for (int r = 0; r < 4; r++)
                s_alpha_w[w][mt * 16 + quad * 4 + r] = part[mt][r];
    }
    __syncthreads();
    if (t < 64) {
        float a = s_alpha_w[0][t] + s_alpha_w[1][t] + s_alpha_w[2][t] + s_alpha_w[3][t];
        s_alpha[t] = (t < LL) ? a * s_flag[t] : 0.f;
    }
    __syncthreads();
    // readout from sA (bf16 normalized seq_hidden) + l2norm
    float so = 0;
    for (int l = 0; l < LL; l++) so += s_alpha[l] * (float)sA[l][t];
    float ss = so * so;
    for (int o = 32; o; o >>= 1) ss += __shfl_xor(ss, o);
    if (lane == 0) s_red[w] = ss;
    __syncthreads();
    float tot = s_red[0] + s_red[1] + s_red[2] + s_red[3];
    float inv = 1.0f / fmaxf(sqrtf(tot), EPSV);
    so_n[b * DD + t] = (bf16)(so * inv);
}
__global__ __launch_bounds__(256) void k_attn(const int* __restrict__ item_seq,
                                              const int* __restrict__ alias_item,
                                              const int* __restrict__ alias_cate,
                                              const float* __restrict__ nodes_h,
                                              const void* __restrict__ q1_w, const void* __restrict__ q1_b,
                                              const void* __restrict__ v_w, const bf16* __restrict__ q2wT,
                                              const int* __restrict__ flag, bf16* __restrict__ so_n) {
    __shared__ bf16 sA[64][DD + APAD];
    __shared__ float s_q1[DD], s_vw[DD], s_ht[DD];
    __shared__ float s_alpha_w[4][64];
    __shared__ float s_alpha[64];
    __shared__ float s_flag[64];
    __shared__ float s_red[4];
    __shared__ int s_ai[64], s_ac[64];
    __shared__ int s_li;
    if (*flag) attn_body<bf16>(item_seq, alias_item, alias_cate, nodes_h,
                               (const bf16*)q1_w, (const bf16*)q1_b, (const bf16*)v_w,
                               q2wT, so_n, sA, s_q1, s_vw, s_ht, s_alpha_w, s_alpha,
                               s_flag, s_red, s_ai, s_ac, &s_li);
    else       attn_body<float>(item_seq, alias_item, alias_cate, nodes_h,
                                (const float*)q1_w, (const float*)q1_b, (const float*)v_w,
                                q2wT, so_n, sA, s_q1, s_vw, s_ht, s_alpha_w, s_alpha,
                                s_flag, s_red, s_ai, s_ac, &s_li);
}

// ---------------- K6 v2: scores = 16 * so_n @ l2norm(item_emb)^T
#define NT 32
#define PAD 8
template <typename T, typename TO>
__device__ __forceinline__ void scores_body(const bf16* so_n, const T* emb, const int* item_cates,
                                            TO* out, bf16 (*sB)[DD + PAD]) {
    int t = threadIdx.x;
    long n0 = (long)blockIdx.x * NT;
    {   // stage + normalize B tile: 32 item rows, 8 threads per row
        int r = t >> 3, j = t & 7;
        long item = n0 + r;
        int cate = item_cates[item];
        const T* ip = emb + item * HH;
        const T* cp = emb + (long)cate * HH;
        float v[32];
#pragma unroll
        for (int k = 0; k < 16; k++) v[k]      = (float)ip[j * 16 + k];
#pragma unroll
        for (int k = 0; k < 16; k++) v[16 + k] = (float)cp[j * 16 + k];
        float s = 0;
#pragma unroll
        for (int k = 0; k < 32; k++) s += v[k] * v[k];
        s += __shfl_xor(s, 1); s += __shfl_xor(s, 2); s += __shfl_xor(s, 4);
        float inv = 1.0f / fmaxf(sqrtf(s), EPSV);
#pragma unroll
        for (int k = 0; k < 16; k++) sB[r][j * 16 + k]       = (bf16)(v[k] * inv);
#pragma unroll
        for (int k = 0; k < 16; k++) sB[r][128 + j * 16 + k] = (bf16)(v[16 + k] * inv);
    }
    __syncthreads();
    int w = t >> 6, lane = t & 63, quad = lane >> 4, r16 = lane & 15;
    bf16x8 bf[2][8];
#pragma unroll
    for (int h = 0; h < 2; h++)
#pragma unroll
        for (int kc = 0; kc < 8; kc++)
            bf[h][kc] = *(const bf16x8*)&sB[h * 16 + r16][kc * 32 + quad * 8];
    for (int m0 = 0; m0 < 8; m0++) {
        int mrow = m0 * 64 + w * 16 + r16;
        const bf16* ap = so_n + (long)mrow * DD + quad * 8;
        bf16x8 a[8];
#pragma unroll
        for (int kc = 0; kc < 8; kc++) a[kc] = *(const bf16x8*)(ap + kc * 32);
        f32x4 acc0 = {0, 0, 0, 0}, acc1 = {0, 0, 0, 0};
#pragma unroll
        for (int kc = 0; kc < 8; kc++) {
            acc0 = __builtin_amdgcn_mfma_f32_16x16x32_bf16(a[kc], bf[0][kc], acc0, 0, 0, 0);
            acc1 = __builtin_amdgcn_mfma_f32_16x16x32_bf16(a[kc], bf[1][kc], acc1, 0, 0, 0);
        }
        int row_base = m0 * 64 + w * 16 + quad * 4;
#pragma unroll
        for (int r = 0; r < 4; r++) {
            out[(long)(row_base + r) * ITEMS + n0 + r16]      = (TO)(acc0[r] * 16.0f);
            out[(long)(row_base + r) * ITEMS + n0 + r16 + 16] = (TO)(acc1[r] * 16.0f);
        }
    }
}
__global__ __launch_bounds__(256) void k_scores(const bf16* __restrict__ so_n,
                                                const void* __restrict__ emb,
                                                const int* __restrict__ item_cates,
                                                const int* __restrict__ flag,
                                                void* __restrict__ out) {
    __shared__ bf16 sB[NT][DD + PAD];
    if (*flag) scores_body<bf16, bf16>(so_n, (const bf16*)emb, item_cates, (bf16*)out, sB);
    else       scores_body<float, float>(so_n, (const float*)emb, item_cates, (float*)out, sB);
}

extern "C" void kernel_launch(void* const* d_in, const int* in_sizes, int n_in,
                              void* d_out, int out_size, void* d_ws, size_t ws_size,
                              hipStream_t stream) {
    const int* item_seq   = (const int*)d_in[0];
    const int* nodes      = (const int*)d_in[2];
    const void* hn_adj    = d_in[3];
    const int* alias_item = (const int*)d_in[4];
    const int* alias_cate = (const int*)d_in[5];
    const void* emb       = d_in[6];
    const int* item_cates = (const int*)d_in[7];
    const void* w_edge    = d_in[8];
    const void* w_node    = d_in[9];
    const void* q1_w      = d_in[10];
    const void* q1_b      = d_in[11];
    const void* q2_w      = d_in[12];
    const void* v_w       = d_in[13];

    // ws layout (total 17,170,688 B — well under the proven-safe 43.25 MB high-water mark)
    char* ws = (char*)d_ws;
    int*   flag    = (int*)ws;                       //       256 B
    bf16*  q2wT    = (bf16*)(ws + 256);              //   131,072 B
    bf16*  so_n    = (bf16*)(ws + 131328);           //   262,144 B
    float* nodes_h = (float*)(ws + 393472);          // 16,777,216 B

    k_detect<<<1, 256, 0, stream>>>((const unsigned int*)hn_adj, flag);
    k_prep<<<256, 256, 0, stream>>>(q2_w, flag, q2wT);
    k_nodes_norm<<<8192, 256, 0, stream>>>(nodes, emb, flag, nodes_h);
    k_hgnn<<<512, 256, 0, stream>>>(hn_adj, w_edge, w_node, flag, nodes_h);
    k_attn<<<512, 256, 0, stream>>>(item_seq, alias_item, alias_cate, nodes_h,
                                    q1_w, q1_b, v_w, q2wT, flag, so_n);
    k_scores<<<3125, 256, 0, stream>>>(so_n, emb, item_cates, flag, d_out);
}